// Round 1
// baseline (257.354 us; speedup 1.0000x reference)
//
#include <hip/hip_runtime.h>
#include <hip/hip_bf16.h>

// Problem constants
// B=2, S=2048, D=1024, H=16, HD=64, M = B*S = 4096

typedef __attribute__((ext_vector_type(8))) short short8;   // 8 bf16 = 4 VGPR (MFMA A/B frag)
typedef __attribute__((ext_vector_type(4))) short short4v;  // 4 bf16
typedef __attribute__((ext_vector_type(4))) float f32x4;    // MFMA C/D frag

static __device__ __forceinline__ short f2bf(float f) {
    union { float f; unsigned u; } c; c.f = f;
    unsigned r = c.u + 0x7fff + ((c.u >> 16) & 1);   // RNE; inputs are finite
    return (short)(r >> 16);
}

// ---------------------------------------------------------------------------
// Weight transpose + bf16 cast: W[K=1024][N=1024] f32 -> Wt[N][K] bf16.
// 4 weight matrices selected by blockIdx.z, outputs contiguous (2MB each).
// ---------------------------------------------------------------------------
__global__ __launch_bounds__(256) void wtrans(
    const float* __restrict__ W0, const float* __restrict__ W1,
    const float* __restrict__ W2, const float* __restrict__ W3,
    short* __restrict__ Out)
{
    const float* W = blockIdx.z == 0 ? W0 : blockIdx.z == 1 ? W1
                   : blockIdx.z == 2 ? W2 : W3;
    short* O = Out + ((size_t)blockIdx.z << 20);
    __shared__ float tile[32][33];
    const int k0 = blockIdx.x * 32, n0 = blockIdx.y * 32;
    const int tx = threadIdx.x, ty = threadIdx.y;  // (32,8)
    #pragma unroll
    for (int j = 0; j < 32; j += 8)
        tile[ty + j][tx] = W[(k0 + ty + j) * 1024 + n0 + tx];
    __syncthreads();
    #pragma unroll
    for (int j = 0; j < 32; j += 8)
        O[(n0 + ty + j) * 1024 + k0 + tx] = f2bf(tile[tx][ty + j]);
}

// ---------------------------------------------------------------------------
// GEMM: Out = scale * (A[4096x1024] @ Wt^T + bias). Wt is [N][K] bf16.
// AMODE: 0 = A is f32 (projections), 1 = A is bf16 (final proj).
// OMODE: 0 = bf16 head-split [B,H,S,64]   (Q with scale=1/8, K)
//        1 = bf16 transposed  [B,H,64,S]  (V)
//        2 = f32 flat [4096][1024]        (final output)
// 128x128 tile, BK=32, 4 waves each owning a 64x64 quadrant (4x4 frags of
// mfma_f32_16x16x32_bf16). LDS rows padded +8 bf16 for bank-conflict-free
// ds_read_b128 fragment reads.
// ---------------------------------------------------------------------------
template<int AMODE, int OMODE>
__global__ __launch_bounds__(256) void gemm_k(
    const void* __restrict__ Ap, const short* __restrict__ Bt,
    const float* __restrict__ bias, void* __restrict__ Out, float scale)
{
    __shared__ short Al[128][40];
    __shared__ short Bl[128][40];
    const int t = threadIdx.x;
    const int m0 = blockIdx.x * 128, n0 = blockIdx.y * 128;
    const int lane = t & 63, w = t >> 6;
    const int lm = lane & 15, lg = lane >> 4;
    const int wr = w >> 1, wc = w & 1;

    f32x4 acc[4][4] = {};

    for (int k0 = 0; k0 < 1024; k0 += 32) {
        // --- stage A tile (128 x 32) ---
        if (AMODE == 0) {
            const float* A = (const float*)Ap;
            const int r = t >> 3, c = t & 7;
            #pragma unroll
            for (int j = 0; j < 4; ++j) {
                const float4 v = *(const float4*)(A + (m0 + r + j * 32) * 1024 + k0 + c * 4);
                short4v sv;
                sv[0] = f2bf(v.x); sv[1] = f2bf(v.y); sv[2] = f2bf(v.z); sv[3] = f2bf(v.w);
                *(short4v*)&Al[r + j * 32][c * 4] = sv;
            }
        } else {
            const short* A = (const short*)Ap;
            const int r = t >> 2, c = t & 3;
            #pragma unroll
            for (int j = 0; j < 2; ++j)
                *(short8*)&Al[r + j * 64][c * 8] =
                    *(const short8*)(A + (m0 + r + j * 64) * 1024 + k0 + c * 8);
        }
        // --- stage B tile (128 n-rows x 32 k) from Wt[N][K] ---
        {
            const int r = t >> 2, c = t & 3;
            #pragma unroll
            for (int j = 0; j < 2; ++j)
                *(short8*)&Bl[r + j * 64][c * 8] =
                    *(const short8*)(Bt + (n0 + r + j * 64) * 1024 + k0 + c * 8);
        }
        __syncthreads();

        short8 af[4], bfr[4];
        #pragma unroll
        for (int mf = 0; mf < 4; ++mf)
            af[mf] = *(const short8*)&Al[wr * 64 + mf * 16 + lm][lg * 8];
        #pragma unroll
        for (int nf = 0; nf < 4; ++nf)
            bfr[nf] = *(const short8*)&Bl[wc * 64 + nf * 16 + lm][lg * 8];
        #pragma unroll
        for (int mf = 0; mf < 4; ++mf)
            #pragma unroll
            for (int nf = 0; nf < 4; ++nf)
                acc[mf][nf] = __builtin_amdgcn_mfma_f32_16x16x32_bf16(
                    af[mf], bfr[nf], acc[mf][nf], 0, 0, 0);
        __syncthreads();
    }

    // --- epilogue ---  D frag: col = lm, rows = lg*4 + i
    #pragma unroll
    for (int mf = 0; mf < 4; ++mf) {
        const int mb = m0 + wr * 64 + mf * 16 + lg * 4;
        #pragma unroll
        for (int nf = 0; nf < 4; ++nf) {
            const int n = n0 + wc * 64 + nf * 16 + lm;
            const float bs = bias[n];
            if (OMODE == 2) {
                float* O = (float*)Out;
                #pragma unroll
                for (int i = 0; i < 4; ++i)
                    O[(mb + i) * 1024 + n] = scale * (acc[mf][nf][i] + bs);
            } else if (OMODE == 0) {
                short* O = (short*)Out;
                #pragma unroll
                for (int i = 0; i < 4; ++i) {
                    const int m = mb + i;
                    const int addr = (((m >> 11) * 16 + (n >> 6)) * 2048 + (m & 2047)) * 64 + (n & 63);
                    O[addr] = f2bf(scale * (acc[mf][nf][i] + bs));
                }
            } else {  // OMODE 1: Vt [B,H,64,S] — 4 consecutive s per lane
                short* O = (short*)Out;
                short4v sv;
                #pragma unroll
                for (int i = 0; i < 4; ++i)
                    sv[i] = f2bf(scale * (acc[mf][nf][i] + bs));
                const int addr = (((mb >> 11) * 16 + (n >> 6)) * 64 + (n & 63)) * 2048 + (mb & 2047);
                *(short4v*)&O[addr] = sv;
            }
        }
    }
}

// ---------------------------------------------------------------------------
// Flash attention. Q[B,H,S,64] (pre-scaled by 1/8), K[B,H,S,64], V^T[B,H,64,S],
// all bf16. One block = (bh, 64 q-rows); 4 waves x 16 q-rows each; KBLK=64.
// Online softmax with per-row (m, l) in registers, 16-lane shfl reductions.
// P re-laid out through per-wave LDS for the PV MFMA A-operand.
// ---------------------------------------------------------------------------
__global__ __launch_bounds__(256) void attn_k(
    const short* __restrict__ Q, const short* __restrict__ K,
    const short* __restrict__ V, short* __restrict__ Ctx)
{
    __shared__ short Kl[64][72];
    __shared__ short Vl[64][72];
    __shared__ short Pl[4][16][72];
    const int t = threadIdx.x;
    const int qt = blockIdx.x, bh = blockIdx.y;
    const int lane = t & 63, w = t >> 6;
    const int lm = lane & 15, lg = lane >> 4;

    // Q fragment: A[m=q][k], lane holds row lm, k = lg*8 + ks*32 + {0..7}
    short8 qf[2];
    const int qrow = qt * 64 + w * 16 + lm;
    #pragma unroll
    for (int ks = 0; ks < 2; ++ks)
        qf[ks] = *(const short8*)(Q + (bh * 2048 + qrow) * 64 + ks * 32 + lg * 8);

    float m_run[4], l_run[4];
    f32x4 o_acc[4] = {};
    #pragma unroll
    for (int i = 0; i < 4; ++i) { m_run[i] = -3e38f; l_run[i] = 0.f; }

    const int r = t >> 2, cc = (t & 3) * 16;
    const short* Kg = K + (bh * 2048 + r) * 64 + cc;
    const short* Vg = V + (bh * 64 + r) * 2048 + cc;

    for (int kt = 0; kt < 32; ++kt) {
        const int kv0 = kt * 64;
        // stage K tile [64 keys][64 hd] and V^T tile [64 hd][64 keys]
        *(short8*)&Kl[r][cc]     = *(const short8*)(Kg + kv0 * 64);
        *(short8*)&Kl[r][cc + 8] = *(const short8*)(Kg + kv0 * 64 + 8);
        *(short8*)&Vl[r][cc]     = *(const short8*)(Vg + kv0);
        *(short8*)&Vl[r][cc + 8] = *(const short8*)(Vg + kv0 + 8);
        __syncthreads();

        // S = Q K^T : B-frag = K rows (contiguous hd)
        f32x4 sa[4] = {};
        #pragma unroll
        for (int nf = 0; nf < 4; ++nf)
            #pragma unroll
            for (int ks = 0; ks < 2; ++ks) {
                const short8 kf = *(const short8*)&Kl[nf * 16 + lm][ks * 32 + lg * 8];
                sa[nf] = __builtin_amdgcn_mfma_f32_16x16x32_bf16(qf[ks], kf, sa[nf], 0, 0, 0);
            }

        // online softmax; lane holds rows lg*4+i, keys nf*16+lm
        #pragma unroll
        for (int i = 0; i < 4; ++i) {
            float mt = fmaxf(fmaxf(sa[0][i], sa[1][i]), fmaxf(sa[2][i], sa[3][i]));
            #pragma unroll
            for (int d = 1; d < 16; d <<= 1) mt = fmaxf(mt, __shfl_xor(mt, d));
            const float mn = fmaxf(m_run[i], mt);
            const float alpha = __expf(m_run[i] - mn);
            float rs = 0.f;
            #pragma unroll
            for (int nf = 0; nf < 4; ++nf) {
                const float p = __expf(sa[nf][i] - mn);
                sa[nf][i] = p;
                rs += p;
            }
            #pragma unroll
            for (int d = 1; d < 16; d <<= 1) rs += __shfl_xor(rs, d);
            l_run[i] = l_run[i] * alpha + rs;
            m_run[i] = mn;
            #pragma unroll
            for (int nf = 0; nf < 4; ++nf) o_acc[nf][i] *= alpha;
        }

        // P -> per-wave LDS (re-layout for PV A-operand)
        #pragma unroll
        for (int i = 0; i < 4; ++i)
            #pragma unroll
            for (int nf = 0; nf < 4; ++nf)
                Pl[w][lg * 4 + i][nf * 16 + lm] = f2bf(sa[nf][i]);
        __syncthreads();

        // ctx += P V : A-frag = P rows (contiguous keys), B-frag = V^T rows
        short8 pa[2];
        #pragma unroll
        for (int ks = 0; ks < 2; ++ks)
            pa[ks] = *(const short8*)&Pl[w][lm][ks * 32 + lg * 8];
        #pragma unroll
        for (int nf = 0; nf < 4; ++nf)
            #pragma unroll
            for (int ks = 0; ks < 2; ++ks) {
                const short8 vf = *(const short8*)&Vl[nf * 16 + lm][ks * 32 + lg * 8];
                o_acc[nf] = __builtin_amdgcn_mfma_f32_16x16x32_bf16(pa[ks], vf, o_acc[nf], 0, 0, 0);
            }
        __syncthreads();
    }

    // epilogue: ctx[b][q][h*64+hd] bf16, rows lg*4+i, cols nf*16+lm
    const int b = bh >> 4, h = bh & 15;
    #pragma unroll
    for (int i = 0; i < 4; ++i) {
        const float inv = 1.f / l_run[i];
        const int q = qt * 64 + w * 16 + lg * 4 + i;
        #pragma unroll
        for (int nf = 0; nf < 4; ++nf)
            Ctx[(b * 2048 + q) * 1024 + h * 64 + nf * 16 + lm] = f2bf(o_acc[nf][i] * inv);
    }
}

// ---------------------------------------------------------------------------
extern "C" void kernel_launch(void* const* d_in, const int* in_sizes, int n_in,
                              void* d_out, int out_size, void* d_ws, size_t ws_size,
                              hipStream_t stream)
{
    const float* query  = (const float*)d_in[0];
    const float* key_in = (const float*)d_in[1];
    const float* value  = (const float*)d_in[2];
    const float* Wq = (const float*)d_in[3];
    const float* bq = (const float*)d_in[4];
    const float* Wk = (const float*)d_in[5];
    const float* bk = (const float*)d_in[6];
    const float* Wv = (const float*)d_in[7];
    const float* bv = (const float*)d_in[8];
    const float* Wo = (const float*)d_in[9];
    const float* bo = (const float*)d_in[10];
    float* out = (float*)d_out;

    char* ws = (char*)d_ws;
    short* Wt  = (short*)(ws);              // 4 x 2MB bf16 transposed weights
    short* Qh  = (short*)(ws + (8  << 20)); // [B,H,S,64]  8MB (pre-scaled 1/8)
    short* Kh  = (short*)(ws + (16 << 20)); // [B,H,S,64]  8MB
    short* Vt  = (short*)(ws + (24 << 20)); // [B,H,64,S]  8MB
    short* Ctx = (short*)(ws + (32 << 20)); // [B,S,D]     8MB

    hipLaunchKernelGGL(wtrans, dim3(32, 32, 4), dim3(32, 8), 0, stream,
                       Wq, Wk, Wv, Wo, Wt);
    hipLaunchKernelGGL((gemm_k<0, 0>), dim3(32, 8), dim3(256), 0, stream,
                       query, Wt, bq, Qh, 0.125f);
    hipLaunchKernelGGL((gemm_k<0, 0>), dim3(32, 8), dim3(256), 0, stream,
                       key_in, Wt + (1 << 20), bk, Kh, 1.0f);
    hipLaunchKernelGGL((gemm_k<0, 1>), dim3(32, 8), dim3(256), 0, stream,
                       value, Wt + (2 << 20), bv, Vt, 1.0f);
    hipLaunchKernelGGL(attn_k, dim3(32, 32), dim3(256), 0, stream,
                       Qh, Kh, Vt, Ctx);
    hipLaunchKernelGGL((gemm_k<1, 2>), dim3(32, 8), dim3(256), 0, stream,
                       Ctx, Wt + (3 << 20), bo, out, 1.0f);
}